// Round 2
// baseline (517.321 us; speedup 1.0000x reference)
//
#include <hip/hip_runtime.h>

// ---------------------------------------------------------------------------
// TimeSeriesTransformer: X[128,256,128] -> qkv -> softmax(K Q^T) V -> MLP
// Strategy: everything matmul-shaped on bf16 MFMA 16x16x32; W1 GEMM (268 MB
// fp32) is the HBM-bound hot spot -> K-split GEMM, per-split slabs (no
// atomics), fused reduce+bias+sigmoid epilogues.
// R1 change: gemm_ksplit B-staging rewritten reg-staged: fp32 global -> VGPR
// -> convert bf16 ONCE -> transposed LDS [n=128][k=32] with 16B-group XOR
// swizzle. Inner loop: 1 conflict-free ds_read_b128 per fragment (was 8x
// ds_read_b32 with 4-way conflicts + 64 redundant f2bf per lane per chunk).
// R2: identical resubmit (both prior benches failed with container errors —
// infra flake, no counters to act on).
// Workspace requirement: ~43.1 MB.
// ---------------------------------------------------------------------------

#define DI __device__ __forceinline__
#define AS1 __attribute__((address_space(1)))
#define AS3 __attribute__((address_space(3)))

typedef __attribute__((ext_vector_type(4))) float f32x4;
typedef __attribute__((ext_vector_type(8))) short bf16x8;

DI unsigned short f2bf(float f) {      // fp32 -> bf16, round-to-nearest-even
  unsigned int u = __float_as_uint(f);
  u += 0x7fffu + ((u >> 16) & 1u);
  return (unsigned short)(u >> 16);
}

// ---- prep: transpose Qw/Kw/Vw (fp32 [ni][no]) -> bf16 wT [3][no][ni] -------
__global__ __launch_bounds__(256) void prep_wt(const float* __restrict__ Qw,
                                               const float* __restrict__ Kw,
                                               const float* __restrict__ Vw,
                                               unsigned short* __restrict__ wT) {
  int gid = blockIdx.x * 256 + threadIdx.x;   // 0..49151
  int w  = gid >> 14;
  int j  = gid & 16383;
  int no = j >> 7, ni = j & 127;
  const float* src = (w == 0) ? Qw : (w == 1) ? Kw : Vw;
  wT[gid] = f2bf(src[ni * 128 + no]);
}

// ---- projections: q,k row-major bf16 [B*T][128]; v transposed [B][128][256]
__global__ __launch_bounds__(256) void proj_kernel(
    const float* __restrict__ X, const unsigned short* __restrict__ wT,
    const float* __restrict__ Qb, const float* __restrict__ Kb,
    const float* __restrict__ Vb,
    unsigned short* __restrict__ q_ws, unsigned short* __restrict__ k_ws,
    unsigned short* __restrict__ vT_ws) {
  int wv = threadIdx.x >> 6, lane = threadIdx.x & 63;
  int quad = lane >> 4, l15 = lane & 15;
  int R0 = blockIdx.x * 64 + wv * 16;        // 16-row tile per wave

  // A-fragments of X (shared by all 3 projections): A[m=l15][k=quad*8+j]
  bf16x8 af[4];
  const float* xbase = X + (size_t)(R0 + l15) * 128 + quad * 8;
#pragma unroll
  for (int kc = 0; kc < 4; ++kc) {
    f32x4 x0 = *(const f32x4*)(xbase + kc * 32);
    f32x4 x1 = *(const f32x4*)(xbase + kc * 32 + 4);
    bf16x8 a;
#pragma unroll
    for (int j = 0; j < 4; ++j) { a[j] = (short)f2bf(x0[j]); a[4 + j] = (short)f2bf(x1[j]); }
    af[kc] = a;
  }

#pragma unroll
  for (int p = 0; p < 3; ++p) {
    const unsigned short* wt = wT + p * 16384;
    const float* bias = (p == 0) ? Qb : (p == 1) ? Kb : Vb;
#pragma unroll
    for (int nt = 0; nt < 8; ++nt) {
      f32x4 acc = {0.f, 0.f, 0.f, 0.f};
#pragma unroll
      for (int kc = 0; kc < 4; ++kc) {
        bf16x8 b = *(const bf16x8*)(wt + (size_t)(nt * 16 + l15) * 128 + kc * 32 + quad * 8);
        acc = __builtin_amdgcn_mfma_f32_16x16x32_bf16(af[kc], b, acc, 0, 0, 0);
      }
      int no = nt * 16 + l15;
      float bv = bias[no];
#pragma unroll
      for (int r4 = 0; r4 < 4; ++r4) {          // C/D: col=l15, row=quad*4+r4
        int row = R0 + quad * 4 + r4;
        unsigned short val = f2bf(acc[r4] + bv);
        if (p == 0)      q_ws[(size_t)row * 128 + no] = val;
        else if (p == 1) k_ws[(size_t)row * 128 + no] = val;
        else {
          int bb = row >> 8, t = row & 255;
          vT_ws[((size_t)bb * 128 + no) * 256 + t] = val;
        }
      }
    }
  }
}

// ---- attention: per block 64 t-rows of one batch; wave = 16-row tile -------
__global__ __launch_bounds__(256) void attn_kernel(
    const unsigned short* __restrict__ q_ws, const unsigned short* __restrict__ k_ws,
    const unsigned short* __restrict__ vT_ws, unsigned short* __restrict__ r_ws) {
  __shared__ __align__(16) unsigned short p_lds[4][16 * 264];  // pad 264 vs 256
  int wv = threadIdx.x >> 6, lane = threadIdx.x & 63;
  int quad = lane >> 4, l15 = lane & 15;
  int b  = blockIdx.x >> 2;
  int t0 = (blockIdx.x & 3) * 64 + wv * 16;

  // K A-fragments (16 rows of k)
  bf16x8 kf[4];
  const unsigned short* kbase = k_ws + ((size_t)b * 256 + t0 + l15) * 128 + quad * 8;
#pragma unroll
  for (int kc = 0; kc < 4; ++kc) kf[kc] = *(const bf16x8*)(kbase + kc * 32);

  // scores S[16][256]: S[t][s] = k[t]·q[s]
  f32x4 sc[16];
#pragma unroll
  for (int st = 0; st < 16; ++st) {
    f32x4 acc = {0.f, 0.f, 0.f, 0.f};
    const unsigned short* qbase = q_ws + ((size_t)b * 256 + st * 16 + l15) * 128 + quad * 8;
#pragma unroll
    for (int kc = 0; kc < 4; ++kc) {
      bf16x8 qf = *(const bf16x8*)(qbase + kc * 32);   // B[k=kk][n=s]
      acc = __builtin_amdgcn_mfma_f32_16x16x32_bf16(kf[kc], qf, acc, 0, 0, 0);
    }
    sc[st] = acc;
  }

  // softmax over s (row = quad*4+r4, held by 16-lane group x 16 st-regs)
  float inv[4];
#pragma unroll
  for (int r4 = 0; r4 < 4; ++r4) {
    float m = sc[0][r4];
#pragma unroll
    for (int st = 1; st < 16; ++st) m = fmaxf(m, sc[st][r4]);
#pragma unroll
    for (int d = 1; d < 16; d <<= 1) m = fmaxf(m, __shfl_xor(m, d, 64));
    float s = 0.f;
#pragma unroll
    for (int st = 0; st < 16; ++st) { float e = __expf(sc[st][r4] - m); sc[st][r4] = e; s += e; }
#pragma unroll
    for (int d = 1; d < 16; d <<= 1) s += __shfl_xor(s, d, 64);
    inv[r4] = 1.f / s;
  }

  // P (C-layout) -> LDS so it can re-enter MFMA in A-layout
#pragma unroll
  for (int st = 0; st < 16; ++st)
#pragma unroll
    for (int r4 = 0; r4 < 4; ++r4)
      p_lds[wv][(quad * 4 + r4) * 264 + st * 16 + l15] = f2bf(sc[st][r4] * inv[r4]);
  __syncthreads();

  // r = P @ V  (B-frags from vT: B[k=s][n=vv] = vT[vv][s])
  const unsigned short* pbase = &p_lds[wv][l15 * 264 + quad * 8];
#pragma unroll
  for (int vt = 0; vt < 8; ++vt) {
    f32x4 acc = {0.f, 0.f, 0.f, 0.f};
    const unsigned short* vbase = vT_ws + ((size_t)b * 128 + vt * 16 + l15) * 256 + quad * 8;
#pragma unroll
    for (int s8 = 0; s8 < 8; ++s8) {
      bf16x8 pf = *(const bf16x8*)(pbase + s8 * 32);
      bf16x8 vf = *(const bf16x8*)(vbase + s8 * 32);
      acc = __builtin_amdgcn_mfma_f32_16x16x32_bf16(pf, vf, acc, 0, 0, 0);
    }
#pragma unroll
    for (int r4 = 0; r4 < 4; ++r4)
      r_ws[((size_t)b * 256 + t0 + quad * 4 + r4) * 128 + vt * 16 + l15] = f2bf(acc[r4]);
  }
}

// ---- K-split GEMM: out[y] = A[128, Kchunk] @ B[Kchunk, 128-tile] -----------
// A bf16 (lda). B fp32 (ldb) reg-staged: global -> VGPR -> bf16 -> transposed
// LDS tile bt[n=128][k=32] with 16B-slot XOR swizzle slot^=((n>>1)&3)^((n>>3)&3)
// so the wave's fragment reads (ds_read_b128, lanes = 16 different n at the
// same k-slot) are bank-conflict free. Slab stores (no atomics).
__global__ __launch_bounds__(256) void gemm_ksplit(
    const unsigned short* __restrict__ A, int lda,
    const float* __restrict__ B, int ldb,
    float* __restrict__ slab, int ldo, int nChunks) {
  __shared__ __align__(16) unsigned short bt[2][128 * 32];   // 2 x 8 KB bf16
  const int tid  = threadIdx.x;
  const int wv   = tid >> 6, lane = tid & 63;
  const int quad = lane >> 4, l15 = lane & 15;
  const int n0   = blockIdx.x * 128;
  const long k0  = (long)blockIdx.y * nChunks * 32;
  const int m0   = wv * 32;

  // staging mapping: thread owns chunk rows {2kp, 2kp+1}, cols nq*8..nq*8+7
  const int kp = tid >> 4;          // 0..15
  const int nq = tid & 15;          // 0..15
  const int gq = kp >> 2;           // 8-wide k-group (== wave id)
  const int qd = kp & 3;            // dword position inside the 16B slot

  f32x4 acc[2][8];
#pragma unroll
  for (int ms = 0; ms < 2; ++ms)
#pragma unroll
    for (int nt = 0; nt < 8; ++nt) acc[ms][nt] = (f32x4){0.f, 0.f, 0.f, 0.f};

  f32x4 r0, r1, r2, r3;             // staged fp32 (2 rows x 8 cols)
  auto LOAD = [&](int c) {          // issue early; latency hides under compute
    const float* g = B + (size_t)(k0 + c * 32 + 2 * kp) * (size_t)ldb + n0 + nq * 8;
    r0 = *(const f32x4*)(g);
    r1 = *(const f32x4*)(g + 4);
    r2 = *(const f32x4*)(g + ldb);
    r3 = *(const f32x4*)(g + ldb + 4);
  };
  auto WRITE = [&](int pb) {        // convert once + transposed swizzled store
#pragma unroll
    for (int i = 0; i < 8; ++i) {
      int n = nq * 8 + i;
      float lo = (i < 4) ? r0[i] : r1[i - 4];   // row 2kp   (even k)
      float hi = (i < 4) ? r2[i] : r3[i - 4];   // row 2kp+1 (odd k)
      unsigned int pk = (unsigned int)f2bf(lo) | ((unsigned int)f2bf(hi) << 16);
      int d = ((n >> 1) & 3) ^ ((n >> 3) & 3);
      *(unsigned int*)&bt[pb][n * 32 + ((gq ^ d) << 3) + 2 * qd] = pk;
    }
  };

  // fragment-read byte base inside one tile: element (n = nt*16+l15,
  // k = quad*8..quad*8+7) lives at n*64 + ((quad^d(n))<<4); the nt-dependent
  // part of d(n) is just bit1 flipping with nt parity -> two bases.
  const int rb = l15 * 64 + ((quad ^ ((l15 >> 1) & 3) ^ (l15 >> 3)) << 4);

  LOAD(0);
  WRITE(0);
  __syncthreads();

  for (int c = 0; c < nChunks; ++c) {
    const int pb = c & 1;
    if (c + 1 < nChunks) LOAD(c + 1);          // overlaps compute below

    bf16x8 aF[2];
    const unsigned short* abase = A + (size_t)(m0 + l15) * lda + k0 + c * 32 + quad * 8;
    aF[0] = *(const bf16x8*)(abase);
    aF[1] = *(const bf16x8*)(abase + (size_t)16 * lda);

    const char* be = (const char*)&bt[pb][0] + rb;
    const char* bo = (const char*)&bt[pb][0] + (rb ^ 32);
#pragma unroll
    for (int nt = 0; nt < 8; ++nt) {
      bf16x8 bF = *(const bf16x8*)(((nt & 1) ? bo : be) + nt * 1024);
      acc[0][nt] = __builtin_amdgcn_mfma_f32_16x16x32_bf16(aF[0], bF, acc[0][nt], 0, 0, 0);
      acc[1][nt] = __builtin_amdgcn_mfma_f32_16x16x32_bf16(aF[1], bF, acc[1][nt], 0, 0, 0);
    }
    __syncthreads();                 // all waves done reading bt[pb^1] (c-1)
    if (c + 1 < nChunks) {
      WRITE(pb ^ 1);                 // stage chunk c+1
      __syncthreads();               // writes visible before compute(c+1)
    }
  }

  float* out = slab + (size_t)blockIdx.y * (size_t)ldo * 128;
#pragma unroll
  for (int ms = 0; ms < 2; ++ms)
#pragma unroll
    for (int nt = 0; nt < 8; ++nt)
#pragma unroll
      for (int r4 = 0; r4 < 4; ++r4)
        out[(size_t)(m0 + ms * 16 + quad * 4 + r4) * ldo + n0 + nt * 16 + l15] =
            acc[ms][nt][r4];
}

// ---- slab reduce + bias + sigmoid -> bf16 ----------------------------------
__global__ __launch_bounds__(256) void reduce_sig(
    const float* __restrict__ slabs, int nslabs, int slabStride,
    const float* __restrict__ bias, int biasMask, unsigned short* __restrict__ outBf) {
  int i = blockIdx.x * 256 + threadIdx.x;
  float s = 0.f;
  for (int y = 0; y < nslabs; ++y) s += slabs[(size_t)y * slabStride + i];
  s += bias[i & biasMask];
  outBf[i] = f2bf(1.f / (1.f + __expf(-s)));
}

// ---- slab reduce + bias -> fp32 final output -------------------------------
__global__ __launch_bounds__(256) void reduce_bias_out(
    const float* __restrict__ slabs, int nslabs, int slabStride,
    const float* __restrict__ bias, int biasMask, float* __restrict__ outF) {
  int i = blockIdx.x * 256 + threadIdx.x;
  float s = 0.f;
  for (int y = 0; y < nslabs; ++y) s += slabs[(size_t)y * slabStride + i];
  outF[i] = s + bias[i & biasMask];
}

// ---------------------------------------------------------------------------
extern "C" void kernel_launch(void* const* d_in, const int* in_sizes, int n_in,
                              void* d_out, int out_size, void* d_ws, size_t ws_size,
                              hipStream_t stream) {
  const float* X  = (const float*)d_in[0];
  const float* Qw = (const float*)d_in[1];
  const float* Qb = (const float*)d_in[2];
  const float* Kw = (const float*)d_in[3];
  const float* Kb = (const float*)d_in[4];
  const float* Vw = (const float*)d_in[5];
  const float* Vb = (const float*)d_in[6];
  const float* W1 = (const float*)d_in[7];
  const float* b1 = (const float*)d_in[8];
  const float* W2 = (const float*)d_in[9];
  const float* b2 = (const float*)d_in[10];
  const float* W3 = (const float*)d_in[11];
  const float* b3 = (const float*)d_in[12];

  // workspace layout (bytes); regions reused across dead phases. Needs 43.1 MB.
  char* ws = (char*)d_ws;
  unsigned short* wT    = (unsigned short*)(ws + 0);         //  96 KB bf16 W^T x3
  unsigned short* r_ws  = (unsigned short*)(ws + 98304);     // 8.39 MB r bf16
  unsigned short* q_ws  = (unsigned short*)(ws + 8486912);   // 8.39 MB
  unsigned short* k_ws  = (unsigned short*)(ws + 16875520);  // 8.39 MB
  unsigned short* vT_ws = (unsigned short*)(ws + 25264128);  // 8.39 MB
  float* g1 = (float*)(ws + 8486912);                        // 32 MB (over q/k/vT, dead)
  unsigned short* h1bf = (unsigned short*)(ws + 42041344);   // 0.5 MB
  float* g2 = (float*)(ws + 8486912);                        // 16 MB (over g1, dead)
  unsigned short* h2bf = (unsigned short*)(ws + 42565632);   // 0.5 MB
  float* g3 = (float*)(ws + 8486912);                        // 32 MB (over g2, dead)

  prep_wt<<<192, 256, 0, stream>>>(Qw, Kw, Vw, wT);
  proj_kernel<<<512, 256, 0, stream>>>(X, wT, Qb, Kb, Vb, q_ws, k_ws, vT_ws);
  attn_kernel<<<512, 256, 0, stream>>>(q_ws, k_ws, vT_ws, r_ws);
  // h1pre = r @ W1 : K=32768 split 32 ways (512 blocks, 2/CU)
  gemm_ksplit<<<dim3(16, 32), 256, 0, stream>>>(r_ws, 32768, W1, 2048, g1, 2048, 32);
  reduce_sig<<<1024, 256, 0, stream>>>(g1, 32, 262144, b1, 2047, h1bf);
  // h2pre = h1 @ W2 : K=2048 split 16 ways
  gemm_ksplit<<<dim3(16, 16), 256, 0, stream>>>(h1bf, 2048, W2, 2048, g2, 2048, 4);
  reduce_sig<<<1024, 256, 0, stream>>>(g2, 16, 262144, b2, 2047, h2bf);
  // out = h2 @ W3 : K=2048 split 16 ways, N=4096
  gemm_ksplit<<<dim3(32, 16), 256, 0, stream>>>(h2bf, 2048, W3, 4096, g3, 4096, 4);
  reduce_bias_out<<<2048, 256, 0, stream>>>(g3, 16, 524288, b3, 4095, (float*)d_out);
}